// Round 6
// baseline (520.564 us; speedup 1.0000x reference)
//
#include <hip/hip_runtime.h>
#include <cmath>

#define DEV __device__ __forceinline__

namespace {

constexpr int Kp    = 127;          // patch tokens
constexpr int Mrows = 32 * Kp;      // 4064 = B*K
constexpr int Rred  = 128 * Kp;     // 16256 = D*K (flat reduction length)

DEV float q88(float x) {
  float r = rintf(x * 256.0f);                       // round half to even, like jnp.round
  r = fminf(fmaxf(r, -32768.0f), 32767.0f);
  return r * 0.00390625f;
}
DEV float sigmoid_(float x) { return 1.0f / (1.0f + expf(-x)); }

DEV void fma16(const float4 av, const float4 bv, float (&acc)[4][4]) {
  acc[0][0] = fmaf(av.x, bv.x, acc[0][0]); acc[0][1] = fmaf(av.x, bv.y, acc[0][1]);
  acc[0][2] = fmaf(av.x, bv.z, acc[0][2]); acc[0][3] = fmaf(av.x, bv.w, acc[0][3]);
  acc[1][0] = fmaf(av.y, bv.x, acc[1][0]); acc[1][1] = fmaf(av.y, bv.y, acc[1][1]);
  acc[1][2] = fmaf(av.y, bv.z, acc[1][2]); acc[1][3] = fmaf(av.y, bv.w, acc[1][3]);
  acc[2][0] = fmaf(av.z, bv.x, acc[2][0]); acc[2][1] = fmaf(av.z, bv.y, acc[2][1]);
  acc[2][2] = fmaf(av.z, bv.z, acc[2][2]); acc[2][3] = fmaf(av.z, bv.w, acc[2][3]);
  acc[3][0] = fmaf(av.w, bv.x, acc[3][0]); acc[3][1] = fmaf(av.w, bv.y, acc[3][1]);
  acc[3][2] = fmaf(av.w, bv.z, acc[3][2]); acc[3][3] = fmaf(av.w, bv.w, acc[3][3]);
}

// ---------------- K0: quantize small weights (and transpose w_patch to [j][c][d]) -------------
__global__ __launch_bounds__(256) void k_quant(
    const float* __restrict__ wproj, const float* __restrict__ bproj,
    const float* __restrict__ wpatch, const float* __restrict__ bpatch,
    const float* __restrict__ whead, const float* __restrict__ bhead,
    const float* __restrict__ bflat,
    float* __restrict__ wq_proj, float* __restrict__ bq_proj, float* __restrict__ wpq,
    float* __restrict__ bq_patch, float* __restrict__ wq_head, float* __restrict__ bq_head,
    float* __restrict__ bq_flat) {
  int i = blockIdx.x * 256 + threadIdx.x;
  if (i < 262144) {
    int j = i >> 14;          // /16384
    int c = (i >> 7) & 127;
    int d = i & 127;
    wpq[i] = q88(wpatch[(d * 128 + c) * 16 + j]);   // w_patch[d][c][j] -> wpq[j][c][d]
  }
  int t = i - 262144;
  if (t >= 0) {
    if      (t < 1024) wq_proj[t]         = q88(wproj[t]);
    else if (t < 1152) bq_proj[t - 1024]  = q88(bproj[t - 1024]);
    else if (t < 1280) bq_patch[t - 1152] = q88(bpatch[t - 1152]);
    else if (t < 1536) wq_head[t - 1280]  = q88(whead[t - 1280]);
    else if (t < 1538) bq_head[t - 1536]  = q88(bhead[t - 1536]);
    else if (t < 4610) bq_flat[t - 1538]  = q88(bflat[t - 1538]);
  }
}

// ---------------- K1: 1x1 conv (proj) -> xpq[b][l][c] (quantized) ----------------------------
__global__ __launch_bounds__(256) void k_proj(const float* __restrict__ x, const float* __restrict__ wq,
                                              const float* __restrict__ bq, float* __restrict__ xpq) {
  int bl0 = blockIdx.x * 16;          // 16 (b,l) rows per block; grid 2048
  int tid = threadIdx.x;
  __shared__ float xs[128];
  if (tid < 128) xs[tid] = q88(x[(size_t)bl0 * 8 + tid]);
  __syncthreads();
  int o = tid & 127;
  int half = tid >> 7;                // 0,1
  float wv[8];
#pragma unroll
  for (int c = 0; c < 8; ++c) wv[c] = wq[o * 8 + c];
  float bb = bq[o];
#pragma unroll
  for (int il = 0; il < 8; ++il) {
    int l_loc = half * 8 + il;
    float acc = bb;
#pragma unroll
    for (int c = 0; c < 8; ++c) acc = fmaf(xs[l_loc * 8 + c], wv[c], acc);
    xpq[(size_t)(bl0 + l_loc) * 128 + o] = q88(acc);
  }
}

// ---------------- K2: patch conv as 16 accumulated GEMMs, j-split x4 -------------------------
__global__ __launch_bounds__(256) void k_patch(const float* __restrict__ xpq, const float* __restrict__ wpq,
                                               float* __restrict__ partJ) {
  __shared__ __align__(16) float As[128][36];
  int mt = blockIdx.x, jg = blockIdx.y;
  int tid = threadIdx.x;
  int mr = tid & 31, c0 = (tid >> 5) * 16;
  int tn = tid & 31, tm8 = tid >> 5;
  int m0 = mt * 32;
  int g = m0 + mr;
  int bb = g / 127, kq = g % 127;
  float acc[4][4] = {};
  for (int jj = 0; jj < 4; ++jj) {
    int j = jg * 4 + jj;
    const float* src = xpq + ((size_t)bb * 1024 + kq * 8 + j) * 128 + c0;
    __syncthreads();
#pragma unroll
    for (int q = 0; q < 4; ++q) {
      float4 v = *reinterpret_cast<const float4*>(src + q * 4);
      As[c0 + q * 4 + 0][mr] = v.x;
      As[c0 + q * 4 + 1][mr] = v.y;
      As[c0 + q * 4 + 2][mr] = v.z;
      As[c0 + q * 4 + 3][mr] = v.w;
    }
    __syncthreads();
    const float* wp = wpq + (size_t)j * 16384 + tn * 4;
#pragma unroll 4
    for (int c = 0; c < 128; ++c) {
      float4 bv = *reinterpret_cast<const float4*>(wp + c * 128);
      float4 av = *reinterpret_cast<const float4*>(&As[c][tm8 * 4]);
      fma16(av, bv, acc);
    }
  }
  float* dst = partJ + ((size_t)jg * Mrows + m0) * 128 + tn * 4;
#pragma unroll
  for (int i = 0; i < 4; ++i) {
    float4 o4 = make_float4(acc[i][0], acc[i][1], acc[i][2], acc[i][3]);
    *reinterpret_cast<float4*>(dst + (size_t)(tm8 * 4 + i) * 128) = o4;
  }
}

// ---------------- K3: combine j-partials + bias, q88, add positional encoding ----------------
__global__ __launch_bounds__(256) void k_combine(const float* __restrict__ partJ, const float* __restrict__ bqp,
                                                 const float* __restrict__ pe, const float* __restrict__ pesc,
                                                 float* __restrict__ h) {
  int i = blockIdx.x * 256 + threadIdx.x;  // < 520192
  int n = i & 127;
  int gq = i >> 7;
  int k = gq % 127;
  float s = partJ[i] + partJ[520192 + i] + partJ[2 * 520192 + i] + partJ[3 * 520192 + i] + bqp[n];
  h[i] = q88(s) + pesc[0] * pe[k * 128 + n];
}

// ---------------- K4: LN + (hn@Win->silu->u) AND (hn@Wgate->silu->g) in one block -------------
__global__ __launch_bounds__(256) void k_ln_ug2(const float* __restrict__ h, const float* __restrict__ lng,
                                                const float* __restrict__ lnb, const float* __restrict__ Win,
                                                const float* __restrict__ Wgate, float* __restrict__ u,
                                                float* __restrict__ gbuf) {
  __shared__ __align__(16) float As[128][36];
  __shared__ float2 lnpart[8][32];
  __shared__ float mean_s[32], inv_s[32];
  int tid = threadIdx.x;
  int mr = tid & 31, c0 = (tid >> 5) * 16;
  int m0 = blockIdx.x * 32;
  const float* src = h + (size_t)(m0 + mr) * 128 + c0;
  float s1 = 0.f, s2 = 0.f;
#pragma unroll
  for (int q = 0; q < 4; ++q) {
    float4 v = *reinterpret_cast<const float4*>(src + q * 4);
    As[c0 + q * 4 + 0][mr] = v.x;
    As[c0 + q * 4 + 1][mr] = v.y;
    As[c0 + q * 4 + 2][mr] = v.z;
    As[c0 + q * 4 + 3][mr] = v.w;
    s1 += v.x + v.y + v.z + v.w;
    s2 = fmaf(v.x, v.x, s2); s2 = fmaf(v.y, v.y, s2);
    s2 = fmaf(v.z, v.z, s2); s2 = fmaf(v.w, v.w, s2);
  }
  lnpart[tid >> 5][mr] = make_float2(s1, s2);
  __syncthreads();
  if (tid < 32) {
    float s = 0.f, ss = 0.f;
#pragma unroll
    for (int j = 0; j < 8; ++j) { float2 p = lnpart[j][tid]; s += p.x; ss += p.y; }
    float mn = s * (1.0f / 128.0f);
    float var = ss * (1.0f / 128.0f) - mn * mn;
    mean_s[tid] = mn;
    inv_s[tid] = rsqrtf(var + 1e-5f);
  }
  __syncthreads();
  float mnv = mean_s[mr], invv = inv_s[mr];
#pragma unroll
  for (int q = 0; q < 16; ++q) {
    int c = c0 + q;
    As[c][mr] = (As[c][mr] - mnv) * invv * lng[c] + lnb[c];
  }
  __syncthreads();
  int tn = tid & 31, tm8 = tid >> 5;
  float accU[4][4] = {}, accG[4][4] = {};
  const float* wpU = Win + tn * 4;
  const float* wpG = Wgate + tn * 4;
#pragma unroll 2
  for (int c = 0; c < 128; ++c) {
    float4 av = *reinterpret_cast<const float4*>(&As[c][tm8 * 4]);
    float4 bu = *reinterpret_cast<const float4*>(wpU + c * 128);
    fma16(av, bu, accU);
    float4 bg = *reinterpret_cast<const float4*>(wpG + c * 128);
    fma16(av, bg, accG);
  }
  float* dstU = u + (size_t)m0 * 128 + tn * 4;
  float* dstG = gbuf + (size_t)m0 * 128 + tn * 4;
#pragma unroll
  for (int i = 0; i < 4; ++i) {
    float4 o4;
    { float xq = q88(accU[i][0]); o4.x = q88(xq * sigmoid_(xq)); }
    { float xq = q88(accU[i][1]); o4.y = q88(xq * sigmoid_(xq)); }
    { float xq = q88(accU[i][2]); o4.z = q88(xq * sigmoid_(xq)); }
    { float xq = q88(accU[i][3]); o4.w = q88(xq * sigmoid_(xq)); }
    *reinterpret_cast<float4*>(dstU + (size_t)(tm8 * 4 + i) * 128) = o4;
    float4 g4;
    { float xq = q88(accG[i][0]); g4.x = q88(xq * sigmoid_(xq)); }
    { float xq = q88(accG[i][1]); g4.y = q88(xq * sigmoid_(xq)); }
    { float xq = q88(accG[i][2]); g4.z = q88(xq * sigmoid_(xq)); }
    { float xq = q88(accG[i][3]); g4.w = q88(xq * sigmoid_(xq)); }
    *reinterpret_cast<float4*>(dstG + (size_t)(tm8 * 4 + i) * 128) = g4;
  }
}

// ---------------- K5: fused lam GEMM + sigmoid + sequential scan + p=y*g ---------------------
// grid (32 b, 4 d-quarters), 256 threads. u,g slices staged once; per t-tile:
// stage wdt tile -> GEMM (t,d) -> q88(sigmoid(q88(.+b))) -> in-LDS scan (reg state) -> p.
__global__ __launch_bounds__(256) void k_lam_scan(const float* __restrict__ u, const float* __restrict__ gbuf,
                                                  const float* __restrict__ wdt, const float* __restrict__ bdt,
                                                  float* __restrict__ p) {
  __shared__ float Us[127][33];
  __shared__ float Gs[127][33];
  __shared__ float Wt[32][128];
  __shared__ float Lt[32][33];
  __shared__ float Pt[32][33];
  int b = blockIdx.x, d0 = blockIdx.y * 32;
  int tid = threadIdx.x;
  // stage u,g slices: [127][32]
  {
    int d = tid & 31;
    int kb = tid >> 5;
#pragma unroll
    for (int pass = 0; pass < 16; ++pass) {
      int k = kb + pass * 8;
      if (k < 127) {
        size_t idx = ((size_t)b * 127 + k) * 128 + d0 + d;
        Us[k][d] = u[idx];
        Gs[k][d] = gbuf[idx];
      }
    }
  }
  __syncthreads();
  int dg = tid & 31, t4 = tid >> 5;
  float s = 0.f;                              // scan state (threads 0..31)
  for (int tt = 0; tt < 4; ++tt) {
    int t0 = tt * 32;
    int tn_tile = (t0 + 32 <= 127) ? 32 : (127 - t0);   // 32,32,32,31
    // stage wdt tile [t][k]
#pragma unroll
    for (int pass = 0; pass < 16; ++pass) {
      int e = pass * 256 + tid;      // 0..4095
      int t = e >> 7, k = e & 127;
      float v = 0.f;
      if (k < 127 && t < tn_tile) v = wdt[(t0 + t) * 127 + k];
      Wt[t][k] = v;
    }
    __syncthreads();
    // GEMM: thread -> d = dg, t = t4*4 + j
    float a0 = 0.f, a1 = 0.f, a2 = 0.f, a3 = 0.f;
    const int tb = t4 * 4;
#pragma unroll 4
    for (int k = 0; k < 127; ++k) {
      float a = Us[k][dg];
      a0 = fmaf(a, Wt[tb + 0][k], a0);
      a1 = fmaf(a, Wt[tb + 1][k], a1);
      a2 = fmaf(a, Wt[tb + 2][k], a2);
      a3 = fmaf(a, Wt[tb + 3][k], a3);
    }
    if (tb + 0 < tn_tile) Lt[tb + 0][dg] = q88(sigmoid_(q88(a0 + bdt[t0 + tb + 0])));
    if (tb + 1 < tn_tile) Lt[tb + 1][dg] = q88(sigmoid_(q88(a1 + bdt[t0 + tb + 1])));
    if (tb + 2 < tn_tile) Lt[tb + 2][dg] = q88(sigmoid_(q88(a2 + bdt[t0 + tb + 2])));
    if (tb + 3 < tn_tile) Lt[tb + 3][dg] = q88(sigmoid_(q88(a3 + bdt[t0 + tb + 3])));
    __syncthreads();
    // sequential scan over this tile (threads 0..31 own one d each)
    if (tid < 32) {
      int d = tid;
      for (int j = 0; j < tn_tile; ++j) {
        float lm = Lt[j][d];
        float uu = Us[t0 + j][d];
        s = lm * s + (1.0f - lm) * uu;
        Pt[j][d] = s * Gs[t0 + j][d];
      }
    }
    __syncthreads();
    // write p tile coalesced
#pragma unroll
    for (int pass = 0; pass < 4; ++pass) {
      int e = pass * 256 + tid;
      int t = e >> 5, d = e & 31;
      if (t < tn_tile)
        p[((size_t)b * 127 + t0 + t) * 128 + d0 + d] = Pt[t][d];
    }
    __syncthreads();  // Wt/Lt/Pt reused next tile
  }
}

// ---------------- K6: fused (h += p@Wout) -> LN -> u/g GEMMs -> silu -------------------------
__global__ __launch_bounds__(256) void k_out_ln_ug(
    const float* __restrict__ p, const float* __restrict__ Wout, float* __restrict__ h,
    const float* __restrict__ lng, const float* __restrict__ lnb,
    const float* __restrict__ Win, const float* __restrict__ Wgate,
    float* __restrict__ u, float* __restrict__ gbuf) {
  __shared__ __align__(16) float As[128][36];
  __shared__ float2 lnpart[8][32];
  __shared__ float mean_s[32], inv_s[32];
  int tid = threadIdx.x;
  int mr = tid & 31, c0 = (tid >> 5) * 16;
  int m0 = blockIdx.x * 32;
  // stage p rows (transposed into As[c][mr])
  {
    const float* src = p + (size_t)(m0 + mr) * 128 + c0;
#pragma unroll
    for (int q = 0; q < 4; ++q) {
      float4 v = *reinterpret_cast<const float4*>(src + q * 4);
      As[c0 + q * 4 + 0][mr] = v.x;
      As[c0 + q * 4 + 1][mr] = v.y;
      As[c0 + q * 4 + 2][mr] = v.z;
      As[c0 + q * 4 + 3][mr] = v.w;
    }
  }
  __syncthreads();
  int tn = tid & 31, tm8 = tid >> 5;
  float acc[4][4] = {};
  {
    const float* wp = Wout + tn * 4;
#pragma unroll 4
    for (int c = 0; c < 128; ++c) {
      float4 bv = *reinterpret_cast<const float4*>(wp + c * 128);
      float4 av = *reinterpret_cast<const float4*>(&As[c][tm8 * 4]);
      fma16(av, bv, acc);
    }
  }
  // hv = h + acc; write back h
  float4 hv[4];
  {
    float* hdst = h + (size_t)m0 * 128 + tn * 4;
#pragma unroll
    for (int i = 0; i < 4; ++i) {
      hv[i] = *reinterpret_cast<float4*>(hdst + (size_t)(tm8 * 4 + i) * 128);
      hv[i].x += acc[i][0]; hv[i].y += acc[i][1]; hv[i].z += acc[i][2]; hv[i].w += acc[i][3];
      *reinterpret_cast<float4*>(hdst + (size_t)(tm8 * 4 + i) * 128) = hv[i];
    }
  }
  __syncthreads();                 // all GEMM reads of As done
  // restage hv transposed: As[c][row]
#pragma unroll
  for (int i = 0; i < 4; ++i) {
    int row = tm8 * 4 + i;
    As[tn * 4 + 0][row] = hv[i].x;
    As[tn * 4 + 1][row] = hv[i].y;
    As[tn * 4 + 2][row] = hv[i].z;
    As[tn * 4 + 3][row] = hv[i].w;
  }
  __syncthreads();
  // LN stats (identical order to k_ln_ug2)
  {
    float s1 = 0.f, s2 = 0.f;
#pragma unroll
    for (int q = 0; q < 4; ++q) {
      float vx = As[c0 + q * 4 + 0][mr];
      float vy = As[c0 + q * 4 + 1][mr];
      float vz = As[c0 + q * 4 + 2][mr];
      float vw = As[c0 + q * 4 + 3][mr];
      s1 += vx + vy + vz + vw;
      s2 = fmaf(vx, vx, s2); s2 = fmaf(vy, vy, s2);
      s2 = fmaf(vz, vz, s2); s2 = fmaf(vw, vw, s2);
    }
    lnpart[tid >> 5][mr] = make_float2(s1, s2);
  }
  __syncthreads();
  if (tid < 32) {
    float s = 0.f, ss = 0.f;
#pragma unroll
    for (int j = 0; j < 8; ++j) { float2 pp = lnpart[j][tid]; s += pp.x; ss += pp.y; }
    float mn = s * (1.0f / 128.0f);
    float var = ss * (1.0f / 128.0f) - mn * mn;
    mean_s[tid] = mn;
    inv_s[tid] = rsqrtf(var + 1e-5f);
  }
  __syncthreads();
  {
    float mnv = mean_s[mr], invv = inv_s[mr];
#pragma unroll
    for (int q = 0; q < 16; ++q) {
      int c = c0 + q;
      As[c][mr] = (As[c][mr] - mnv) * invv * lng[c] + lnb[c];
    }
  }
  __syncthreads();
  // u/g GEMM + silu (identical to k_ln_ug2 tail)
  float accU[4][4] = {}, accG[4][4] = {};
  const float* wpU = Win + tn * 4;
  const float* wpG = Wgate + tn * 4;
#pragma unroll 2
  for (int c = 0; c < 128; ++c) {
    float4 av = *reinterpret_cast<const float4*>(&As[c][tm8 * 4]);
    float4 bu = *reinterpret_cast<const float4*>(wpU + c * 128);
    fma16(av, bu, accU);
    float4 bg = *reinterpret_cast<const float4*>(wpG + c * 128);
    fma16(av, bg, accG);
  }
  float* dstU = u + (size_t)m0 * 128 + tn * 4;
  float* dstG = gbuf + (size_t)m0 * 128 + tn * 4;
#pragma unroll
  for (int i = 0; i < 4; ++i) {
    float4 o4;
    { float xq = q88(accU[i][0]); o4.x = q88(xq * sigmoid_(xq)); }
    { float xq = q88(accU[i][1]); o4.y = q88(xq * sigmoid_(xq)); }
    { float xq = q88(accU[i][2]); o4.z = q88(xq * sigmoid_(xq)); }
    { float xq = q88(accU[i][3]); o4.w = q88(xq * sigmoid_(xq)); }
    *reinterpret_cast<float4*>(dstU + (size_t)(tm8 * 4 + i) * 128) = o4;
    float4 g4;
    { float xq = q88(accG[i][0]); g4.x = q88(xq * sigmoid_(xq)); }
    { float xq = q88(accG[i][1]); g4.y = q88(xq * sigmoid_(xq)); }
    { float xq = q88(accG[i][2]); g4.z = q88(xq * sigmoid_(xq)); }
    { float xq = q88(accG[i][3]); g4.w = q88(xq * sigmoid_(xq)); }
    *reinterpret_cast<float4*>(dstG + (size_t)(tm8 * 4 + i) * 128) = g4;
  }
}

// ---------------- K7: fused (h += p@Wout) -> final LN -> q88 -> transpose to [b][r] ----------
__global__ __launch_bounds__(256) void k_out_lnf(
    const float* __restrict__ p, const float* __restrict__ Wout, const float* __restrict__ h,
    const float* __restrict__ gg, const float* __restrict__ bb, float* __restrict__ xp2q) {
  __shared__ __align__(16) float As[128][36];
  __shared__ float2 lnpart[8][32];
  __shared__ float mean_s[32], inv_s[32];
  int tid = threadIdx.x;
  int mr = tid & 31, c0 = (tid >> 5) * 16;
  int m0 = blockIdx.x * 32;
  {
    const float* src = p + (size_t)(m0 + mr) * 128 + c0;
#pragma unroll
    for (int q = 0; q < 4; ++q) {
      float4 v = *reinterpret_cast<const float4*>(src + q * 4);
      As[c0 + q * 4 + 0][mr] = v.x;
      As[c0 + q * 4 + 1][mr] = v.y;
      As[c0 + q * 4 + 2][mr] = v.z;
      As[c0 + q * 4 + 3][mr] = v.w;
    }
  }
  __syncthreads();
  int tn = tid & 31, tm8 = tid >> 5;
  float acc[4][4] = {};
  {
    const float* wp = Wout + tn * 4;
#pragma unroll 4
    for (int c = 0; c < 128; ++c) {
      float4 bv = *reinterpret_cast<const float4*>(wp + c * 128);
      float4 av = *reinterpret_cast<const float4*>(&As[c][tm8 * 4]);
      fma16(av, bv, acc);
    }
  }
  float4 hv[4];
  {
    const float* hsrc = h + (size_t)m0 * 128 + tn * 4;
#pragma unroll
    for (int i = 0; i < 4; ++i) {
      hv[i] = *reinterpret_cast<const float4*>(hsrc + (size_t)(tm8 * 4 + i) * 128);
      hv[i].x += acc[i][0]; hv[i].y += acc[i][1]; hv[i].z += acc[i][2]; hv[i].w += acc[i][3];
    }
  }
  __syncthreads();
#pragma unroll
  for (int i = 0; i < 4; ++i) {
    int row = tm8 * 4 + i;
    As[tn * 4 + 0][row] = hv[i].x;
    As[tn * 4 + 1][row] = hv[i].y;
    As[tn * 4 + 2][row] = hv[i].z;
    As[tn * 4 + 3][row] = hv[i].w;
  }
  __syncthreads();
  {
    float s1 = 0.f, s2 = 0.f;
#pragma unroll
    for (int q = 0; q < 4; ++q) {
      float vx = As[c0 + q * 4 + 0][mr];
      float vy = As[c0 + q * 4 + 1][mr];
      float vz = As[c0 + q * 4 + 2][mr];
      float vw = As[c0 + q * 4 + 3][mr];
      s1 += vx + vy + vz + vw;
      s2 = fmaf(vx, vx, s2); s2 = fmaf(vy, vy, s2);
      s2 = fmaf(vz, vz, s2); s2 = fmaf(vw, vw, s2);
    }
    lnpart[tid >> 5][mr] = make_float2(s1, s2);
  }
  __syncthreads();
  if (tid < 32) {
    float s = 0.f, ss = 0.f;
#pragma unroll
    for (int j = 0; j < 8; ++j) { float2 pp = lnpart[j][tid]; s += pp.x; ss += pp.y; }
    float mn = s * (1.0f / 128.0f);
    float var = ss * (1.0f / 128.0f) - mn * mn;
    mean_s[tid] = mn;
    inv_s[tid] = rsqrtf(var + 1e-5f);
  }
  __syncthreads();
  {
    float mnv = mean_s[mr], invv = inv_s[mr];
    int row = m0 + mr;
    int b = row / 127, k = row % 127;
#pragma unroll
    for (int q = 0; q < 16; ++q) {
      int c = c0 + q;
      float hn = (As[c][mr] - mnv) * invv * gg[c] + bb[c];
      xp2q[((size_t)b * 128 + c) * 127 + k] = q88(hn);
    }
  }
}

// ---------------- K9: flat contraction, 8b x 4o tile, reg-pipelined staging -----------------
__global__ __launch_bounds__(128) void k_flat(const float* __restrict__ Aq, const float* __restrict__ Wf,
                                              float* __restrict__ partF) {
  __shared__ float As[32][36];    // [r][b] * 2^-8
  __shared__ float Ws[32][132];   // [r][o] rintf(256*w)
  int ot = blockIdx.x, rs = blockIdx.y;
  int tid = threadIdx.x;
  int og = tid & 31, bsub = tid >> 5;
  int o0 = ot * 128;
  int r0 = rs * 256;               // virtual R = 16384, zero-padded past 16256
  float acc[8][4] = {};

  const int wq4 = tid & 3;         // quad-pair within W row
  const int wrow_l = tid >> 2;     // 0..31, +32 per pass
  const int aq = tid >> 5;         // A quad group
  const int ab = tid & 31;         // A b-row

  float4 wreg[4][2];
  float4 areg[2];

  auto loadch = [&](int rb) {
#pragma unroll
    for (int p = 0; p < 4; ++p) {
      const float* wrow = Wf + (size_t)(o0 + wrow_l + 32 * p) * Rred;
#pragma unroll
      for (int q = 0; q < 2; ++q) {
        int rr = rb + wq4 * 8 + q * 4;
        wreg[p][q] = (rr < Rred) ? *reinterpret_cast<const float4*>(wrow + rr)
                                 : make_float4(0.f, 0.f, 0.f, 0.f);
      }
    }
#pragma unroll
    for (int i = 0; i < 2; ++i) {
      int rr = rb + aq * 4 + 16 * i;
      areg[i] = (rr < Rred) ? *reinterpret_cast<const float4*>(Aq + (size_t)ab * Rred + rr)
                            : make_float4(0.f, 0.f, 0.f, 0.f);
    }
  };

  loadch(r0);
  for (int ch = 0; ch < 8; ++ch) {
    __syncthreads();
#pragma unroll
    for (int p = 0; p < 4; ++p) {
      int oc = wrow_l + 32 * p;
#pragma unroll
      for (int q = 0; q < 2; ++q) {
        int rl = wq4 * 8 + q * 4;
        Ws[rl + 0][oc] = rintf(wreg[p][q].x * 256.0f);
        Ws[rl + 1][oc] = rintf(wreg[p][q].y * 256.0f);
        Ws[rl + 2][oc] = rintf(wreg[p][q].z * 256.0f);
        Ws[rl + 3][oc] = rintf(wreg[p][q].w * 256.0f);
      }
    }
#pragma unroll
    for (int i = 0; i < 2; ++i) {
      int rl = aq * 4 + 16 * i;
      As[rl + 0][ab] = areg[i].x * 0.00390625f;
      As[rl + 1][ab] = areg[i].y * 0.00390625f;
      As[rl + 2][ab] = areg[i].z * 0.00390625f;
      As[rl + 3][ab] = areg[i].w * 0.00390625f;
    }
    __syncthreads();
    if (ch < 7) loadch(r0 + (ch + 1) * 32);
#pragma unroll 4
    for (int rl = 0; rl < 32; ++rl) {
      float4 w  = *reinterpret_cast<const float4*>(&Ws[rl][og * 4]);
      float4 a0 = *reinterpret_cast<const float4*>(&As[rl][bsub * 8]);
      float4 a1 = *reinterpret_cast<const float4*>(&As[rl][bsub * 8 + 4]);
      float a[8] = {a0.x, a0.y, a0.z, a0.w, a1.x, a1.y, a1.z, a1.w};
#pragma unroll
      for (int bi = 0; bi < 8; ++bi) {
        acc[bi][0] = fmaf(a[bi], w.x, acc[bi][0]);
        acc[bi][1] = fmaf(a[bi], w.y, acc[bi][1]);
        acc[bi][2] = fmaf(a[bi], w.z, acc[bi][2]);
        acc[bi][3] = fmaf(a[bi], w.w, acc[bi][3]);
      }
    }
  }
#pragma unroll
  for (int bi = 0; bi < 8; ++bi) {
    int b = bsub * 8 + bi;
    float* dst = partF + ((size_t)rs * 32 + b) * 3072 + o0 + og * 4;
    *reinterpret_cast<float4*>(dst) = make_float4(acc[bi][0], acc[bi][1], acc[bi][2], acc[bi][3]);
  }
}

// ---------------- K10: combine r-partials -> y_feat (q88) -> head conv1x1 --------------------
__global__ __launch_bounds__(256) void k_head(const float* __restrict__ partF, const float* __restrict__ bqf,
                                              const float* __restrict__ wqh, const float* __restrict__ bqh,
                                              float* __restrict__ out) {
  int b = blockIdx.x;
  int tid = threadIdx.x;
  __shared__ float yf[3072];
#pragma unroll
  for (int i = 0; i < 12; ++i) {
    int o = tid + 256 * i;
    float s = bqf[o];
    for (int rsq = 0; rsq < 64; ++rsq) s += partF[((size_t)rsq * 32 + b) * 3072 + o];
    yf[o] = q88(s);
  }
  __syncthreads();
  if (tid < 48) {
    int oh = tid / 24, f = tid % 24;
    float acc = bqh[oh];
    for (int d = 0; d < 128; ++d) acc = fmaf(yf[d * 24 + f], wqh[oh * 128 + d], acc);
    out[(size_t)b * 48 + oh * 24 + f] = q88(acc);
  }
}

}  // namespace

extern "C" void kernel_launch(void* const* d_in, const int* in_sizes, int n_in,
                              void* d_out, int out_size, void* d_ws, size_t ws_size,
                              hipStream_t stream) {
  const float* x      = (const float*)d_in[0];
  const float* wproj  = (const float*)d_in[1];
  const float* bproj  = (const float*)d_in[2];
  const float* wpatch = (const float*)d_in[3];
  const float* bpatch = (const float*)d_in[4];
  const float* pe     = (const float*)d_in[5];
  const float* pescal = (const float*)d_in[6];
  const float* lng    = (const float*)d_in[7];
  const float* lnb    = (const float*)d_in[8];
  const float* win    = (const float*)d_in[9];
  const float* wgate  = (const float*)d_in[10];
  const float* wout   = (const float*)d_in[11];
  const float* wdt    = (const float*)d_in[12];
  const float* bdt    = (const float*)d_in[13];
  const float* lnfg   = (const float*)d_in[14];
  const float* lnfb   = (const float*)d_in[15];
  const float* wflat  = (const float*)d_in[16];
  const float* bflat  = (const float*)d_in[17];
  const float* whead  = (const float*)d_in[18];
  const float* bhead  = (const float*)d_in[19];
  float* out = (float*)d_out;
  float* ws  = (float*)d_ws;

  // ws layout (float offsets)
  constexpr size_t O_WQPROJ  = 0;         // 1024
  constexpr size_t O_BQPROJ  = 1024;      // 128
  constexpr size_t O_WPQ     = 2048;      // 262144   [j][c][d]
  constexpr size_t O_BQPATCH = 264192;    // 128
  constexpr size_t O_WQHEAD  = 264320;    // 256
  constexpr size_t O_BQHEAD  = 264576;    // 2 (pad 128)
  constexpr size_t O_BQFLAT  = 264704;    // 3072
  constexpr size_t O_XPQ     = 267776;    // 4194304  [b][l][c]; later reused as partF
  constexpr size_t O_PARTJ   = 4462080;   // 4*520192
  constexpr size_t O_H       = 6542848;   // 520192   [b][k][d]
  constexpr size_t O_U       = 7063040;   // 520192
  constexpr size_t O_G       = 7583232;   // 520192
  constexpr size_t O_P       = 8103424;   // 520192   p = y*g
  constexpr size_t O_XP2Q    = 8623616;   // 520192   [b][r] (= [b][d][k])
  constexpr size_t O_PARTF   = O_XPQ;     // 64*98304; xpq/partJ dead by k_flat

  k_quant<<<(262144 + 4610 + 255) / 256, 256, 0, stream>>>(
      wproj, bproj, wpatch, bpatch, whead, bhead, bflat,
      ws + O_WQPROJ, ws + O_BQPROJ, ws + O_WPQ, ws + O_BQPATCH,
      ws + O_WQHEAD, ws + O_BQHEAD, ws + O_BQFLAT);

  k_proj<<<2048, 256, 0, stream>>>(x, ws + O_WQPROJ, ws + O_BQPROJ, ws + O_XPQ);

  {
    dim3 g(127, 4);
    k_patch<<<g, 256, 0, stream>>>(ws + O_XPQ, ws + O_WPQ, ws + O_PARTJ);
  }
  k_combine<<<2032, 256, 0, stream>>>(ws + O_PARTJ, ws + O_BQPATCH, pe, pescal, ws + O_H);

  k_ln_ug2<<<127, 256, 0, stream>>>(ws + O_H, lng, lnb, win, wgate, ws + O_U, ws + O_G);

  for (int i = 0; i < 4; ++i) {
    dim3 gl(32, 4);
    k_lam_scan<<<gl, 256, 0, stream>>>(ws + O_U, ws + O_G, wdt + (size_t)i * 16129,
                                       bdt + (size_t)i * 127, ws + O_P);
    if (i < 3) {
      k_out_ln_ug<<<127, 256, 0, stream>>>(ws + O_P, wout + (size_t)i * 16384, ws + O_H,
                                           lng + (i + 1) * 128, lnb + (i + 1) * 128,
                                           win + (size_t)(i + 1) * 16384,
                                           wgate + (size_t)(i + 1) * 16384,
                                           ws + O_U, ws + O_G);
    } else {
      k_out_lnf<<<127, 256, 0, stream>>>(ws + O_P, wout + (size_t)i * 16384, ws + O_H,
                                         lnfg, lnfb, ws + O_XP2Q);
    }
  }

  {
    dim3 g(24, 64);
    k_flat<<<g, 128, 0, stream>>>(ws + O_XP2Q, wflat, ws + O_PARTF);
  }
  k_head<<<32, 256, 0, stream>>>(ws + O_PARTF, ws + O_BQFLAT, ws + O_WQHEAD, ws + O_BQHEAD, out);
}

// Round 7
// 402.150 us; speedup vs baseline: 1.2945x; 1.2945x over previous
//
#include <hip/hip_runtime.h>
#include <cmath>

#define DEV __device__ __forceinline__

namespace {

constexpr int Kp    = 127;          // patch tokens
constexpr int Mrows = 32 * Kp;      // 4064 = B*K
constexpr int Rred  = 128 * Kp;     // 16256 = D*K (flat reduction length)

DEV float q88(float x) {
  float r = rintf(x * 256.0f);                       // round half to even, like jnp.round
  r = fminf(fmaxf(r, -32768.0f), 32767.0f);
  return r * 0.00390625f;
}
DEV float sigmoid_(float x) { return 1.0f / (1.0f + expf(-x)); }

DEV void fma16(const float4 av, const float4 bv, float (&acc)[4][4]) {
  acc[0][0] = fmaf(av.x, bv.x, acc[0][0]); acc[0][1] = fmaf(av.x, bv.y, acc[0][1]);
  acc[0][2] = fmaf(av.x, bv.z, acc[0][2]); acc[0][3] = fmaf(av.x, bv.w, acc[0][3]);
  acc[1][0] = fmaf(av.y, bv.x, acc[1][0]); acc[1][1] = fmaf(av.y, bv.y, acc[1][1]);
  acc[1][2] = fmaf(av.y, bv.z, acc[1][2]); acc[1][3] = fmaf(av.y, bv.w, acc[1][3]);
  acc[2][0] = fmaf(av.z, bv.x, acc[2][0]); acc[2][1] = fmaf(av.z, bv.y, acc[2][1]);
  acc[2][2] = fmaf(av.z, bv.z, acc[2][2]); acc[2][3] = fmaf(av.z, bv.w, acc[2][3]);
  acc[3][0] = fmaf(av.w, bv.x, acc[3][0]); acc[3][1] = fmaf(av.w, bv.y, acc[3][1]);
  acc[3][2] = fmaf(av.w, bv.z, acc[3][2]); acc[3][3] = fmaf(av.w, bv.w, acc[3][3]);
}

// ---------------- K0: quantize small weights (and transpose w_patch to [j][c][d]) -------------
__global__ __launch_bounds__(256) void k_quant(
    const float* __restrict__ wproj, const float* __restrict__ bproj,
    const float* __restrict__ wpatch, const float* __restrict__ bpatch,
    const float* __restrict__ whead, const float* __restrict__ bhead,
    const float* __restrict__ bflat,
    float* __restrict__ wq_proj, float* __restrict__ bq_proj, float* __restrict__ wpq,
    float* __restrict__ bq_patch, float* __restrict__ wq_head, float* __restrict__ bq_head,
    float* __restrict__ bq_flat) {
  int i = blockIdx.x * 256 + threadIdx.x;
  if (i < 262144) {
    int j = i >> 14;          // /16384
    int c = (i >> 7) & 127;
    int d = i & 127;
    wpq[i] = q88(wpatch[(d * 128 + c) * 16 + j]);   // w_patch[d][c][j] -> wpq[j][c][d]
  }
  int t = i - 262144;
  if (t >= 0) {
    if      (t < 1024) wq_proj[t]         = q88(wproj[t]);
    else if (t < 1152) bq_proj[t - 1024]  = q88(bproj[t - 1024]);
    else if (t < 1280) bq_patch[t - 1152] = q88(bpatch[t - 1152]);
    else if (t < 1536) wq_head[t - 1280]  = q88(whead[t - 1280]);
    else if (t < 1538) bq_head[t - 1536]  = q88(bhead[t - 1536]);
    else if (t < 4610) bq_flat[t - 1538]  = q88(bflat[t - 1538]);
  }
}

// ---------------- K1: 1x1 conv (proj) -> xpq[b][l][c] (quantized) ----------------------------
__global__ __launch_bounds__(256) void k_proj(const float* __restrict__ x, const float* __restrict__ wq,
                                              const float* __restrict__ bq, float* __restrict__ xpq) {
  int bl0 = blockIdx.x * 16;          // 16 (b,l) rows per block; grid 2048
  int tid = threadIdx.x;
  __shared__ float xs[128];
  if (tid < 128) xs[tid] = q88(x[(size_t)bl0 * 8 + tid]);
  __syncthreads();
  int o = tid & 127;
  int half = tid >> 7;                // 0,1
  float wv[8];
#pragma unroll
  for (int c = 0; c < 8; ++c) wv[c] = wq[o * 8 + c];
  float bb = bq[o];
#pragma unroll
  for (int il = 0; il < 8; ++il) {
    int l_loc = half * 8 + il;
    float acc = bb;
#pragma unroll
    for (int c = 0; c < 8; ++c) acc = fmaf(xs[l_loc * 8 + c], wv[c], acc);
    xpq[(size_t)(bl0 + l_loc) * 128 + o] = q88(acc);
  }
}

// ---------------- K2: patch conv as 16 accumulated GEMMs, j-split x4 -------------------------
__global__ __launch_bounds__(256) void k_patch(const float* __restrict__ xpq, const float* __restrict__ wpq,
                                               float* __restrict__ partJ) {
  __shared__ __align__(16) float As[128][36];
  int mt = blockIdx.x, jg = blockIdx.y;
  int tid = threadIdx.x;
  int mr = tid & 31, c0 = (tid >> 5) * 16;
  int tn = tid & 31, tm8 = tid >> 5;
  int m0 = mt * 32;
  int g = m0 + mr;
  int bb = g / 127, kq = g % 127;
  float acc[4][4] = {};
  for (int jj = 0; jj < 4; ++jj) {
    int j = jg * 4 + jj;
    const float* src = xpq + ((size_t)bb * 1024 + kq * 8 + j) * 128 + c0;
    __syncthreads();
#pragma unroll
    for (int q = 0; q < 4; ++q) {
      float4 v = *reinterpret_cast<const float4*>(src + q * 4);
      As[c0 + q * 4 + 0][mr] = v.x;
      As[c0 + q * 4 + 1][mr] = v.y;
      As[c0 + q * 4 + 2][mr] = v.z;
      As[c0 + q * 4 + 3][mr] = v.w;
    }
    __syncthreads();
    const float* wp = wpq + (size_t)j * 16384 + tn * 4;
#pragma unroll 4
    for (int c = 0; c < 128; ++c) {
      float4 bv = *reinterpret_cast<const float4*>(wp + c * 128);
      float4 av = *reinterpret_cast<const float4*>(&As[c][tm8 * 4]);
      fma16(av, bv, acc);
    }
  }
  float* dst = partJ + ((size_t)jg * Mrows + m0) * 128 + tn * 4;
#pragma unroll
  for (int i = 0; i < 4; ++i) {
    float4 o4 = make_float4(acc[i][0], acc[i][1], acc[i][2], acc[i][3]);
    *reinterpret_cast<float4*>(dst + (size_t)(tm8 * 4 + i) * 128) = o4;
  }
}

// ---------------- K3: combine j-partials + bias, q88, add positional encoding ----------------
__global__ __launch_bounds__(256) void k_combine(const float* __restrict__ partJ, const float* __restrict__ bqp,
                                                 const float* __restrict__ pe, const float* __restrict__ pesc,
                                                 float* __restrict__ h) {
  int i = blockIdx.x * 256 + threadIdx.x;  // < 520192
  int n = i & 127;
  int gq = i >> 7;
  int k = gq % 127;
  float s = partJ[i] + partJ[520192 + i] + partJ[2 * 520192 + i] + partJ[3 * 520192 + i] + bqp[n];
  h[i] = q88(s) + pesc[0] * pe[k * 128 + n];
}

// ---------------- K4: LN + (hn@Win->silu->u) AND (hn@Wgate->silu->g) in one block -------------
__global__ __launch_bounds__(256) void k_ln_ug2(const float* __restrict__ h, const float* __restrict__ lng,
                                                const float* __restrict__ lnb, const float* __restrict__ Win,
                                                const float* __restrict__ Wgate, float* __restrict__ u,
                                                float* __restrict__ gbuf) {
  __shared__ __align__(16) float As[128][36];
  __shared__ float2 lnpart[8][32];
  __shared__ float mean_s[32], inv_s[32];
  int tid = threadIdx.x;
  int mr = tid & 31, c0 = (tid >> 5) * 16;
  int m0 = blockIdx.x * 32;
  const float* src = h + (size_t)(m0 + mr) * 128 + c0;
  float s1 = 0.f, s2 = 0.f;
#pragma unroll
  for (int q = 0; q < 4; ++q) {
    float4 v = *reinterpret_cast<const float4*>(src + q * 4);
    As[c0 + q * 4 + 0][mr] = v.x;
    As[c0 + q * 4 + 1][mr] = v.y;
    As[c0 + q * 4 + 2][mr] = v.z;
    As[c0 + q * 4 + 3][mr] = v.w;
    s1 += v.x + v.y + v.z + v.w;
    s2 = fmaf(v.x, v.x, s2); s2 = fmaf(v.y, v.y, s2);
    s2 = fmaf(v.z, v.z, s2); s2 = fmaf(v.w, v.w, s2);
  }
  lnpart[tid >> 5][mr] = make_float2(s1, s2);
  __syncthreads();
  if (tid < 32) {
    float s = 0.f, ss = 0.f;
#pragma unroll
    for (int j = 0; j < 8; ++j) { float2 p = lnpart[j][tid]; s += p.x; ss += p.y; }
    float mn = s * (1.0f / 128.0f);
    float var = ss * (1.0f / 128.0f) - mn * mn;
    mean_s[tid] = mn;
    inv_s[tid] = rsqrtf(var + 1e-5f);
  }
  __syncthreads();
  float mnv = mean_s[mr], invv = inv_s[mr];
#pragma unroll
  for (int q = 0; q < 16; ++q) {
    int c = c0 + q;
    As[c][mr] = (As[c][mr] - mnv) * invv * lng[c] + lnb[c];
  }
  __syncthreads();
  int tn = tid & 31, tm8 = tid >> 5;
  float accU[4][4] = {}, accG[4][4] = {};
  const float* wpU = Win + tn * 4;
  const float* wpG = Wgate + tn * 4;
#pragma unroll 2
  for (int c = 0; c < 128; ++c) {
    float4 av = *reinterpret_cast<const float4*>(&As[c][tm8 * 4]);
    float4 bu = *reinterpret_cast<const float4*>(wpU + c * 128);
    fma16(av, bu, accU);
    float4 bg = *reinterpret_cast<const float4*>(wpG + c * 128);
    fma16(av, bg, accG);
  }
  float* dstU = u + (size_t)m0 * 128 + tn * 4;
  float* dstG = gbuf + (size_t)m0 * 128 + tn * 4;
#pragma unroll
  for (int i = 0; i < 4; ++i) {
    float4 o4;
    { float xq = q88(accU[i][0]); o4.x = q88(xq * sigmoid_(xq)); }
    { float xq = q88(accU[i][1]); o4.y = q88(xq * sigmoid_(xq)); }
    { float xq = q88(accU[i][2]); o4.z = q88(xq * sigmoid_(xq)); }
    { float xq = q88(accU[i][3]); o4.w = q88(xq * sigmoid_(xq)); }
    *reinterpret_cast<float4*>(dstU + (size_t)(tm8 * 4 + i) * 128) = o4;
    float4 g4;
    { float xq = q88(accG[i][0]); g4.x = q88(xq * sigmoid_(xq)); }
    { float xq = q88(accG[i][1]); g4.y = q88(xq * sigmoid_(xq)); }
    { float xq = q88(accG[i][2]); g4.z = q88(xq * sigmoid_(xq)); }
    { float xq = q88(accG[i][3]); g4.w = q88(xq * sigmoid_(xq)); }
    *reinterpret_cast<float4*>(dstG + (size_t)(tm8 * 4 + i) * 128) = g4;
  }
}

// ---------------- K5: lam = q88(sigmoid(q88(wdt @ u[b] + b_dt))) as tiled GEMM ---------------
// grid (32 b, 4 t-tiles), 256 threads; out tile 32t x 128d; K = 127 (k)
__global__ __launch_bounds__(256) void k_lamg(const float* __restrict__ u, const float* __restrict__ wdt,
                                              const float* __restrict__ bdt, float* __restrict__ lam) {
  __shared__ __align__(16) float Wk[32][36];    // [k][t]
  __shared__ __align__(16) float Us[32][132];   // [k][d]
  int b = blockIdx.x, tt = blockIdx.y;
  int t0 = tt * 32;
  int tid = threadIdx.x;
  int dg = tid & 31, tg = tid >> 5;   // out: t = t0 + tg*4 + ti, d = dg*4 + di
  float acc[4][4] = {};
  const float* ub = u + (size_t)b * (127 * 128);
  for (int k0 = 0; k0 < 127; k0 += 32) {
    __syncthreads();
    {  // stage Wk: wdt[t0+t][k0+k] -> Wk[k][t]
      int k = tid & 31, tl = tid >> 5;
#pragma unroll
      for (int q = 0; q < 4; ++q) {
        int t = tl + 8 * q;
        int tg2 = t0 + t, kg = k0 + k;
        float v = (tg2 < 127 && kg < 127) ? wdt[tg2 * 127 + kg] : 0.f;
        Wk[k][t] = v;
      }
    }
    {  // stage Us: u[b][k0+k][d] -> Us[k][d]
      int dq = tid & 7, k = tid >> 3;
      int kg = k0 + k;
      const float* srcp = ub + (size_t)kg * 128 + dq * 16;
#pragma unroll
      for (int q = 0; q < 4; ++q) {
        float4 v = make_float4(0.f, 0.f, 0.f, 0.f);
        if (kg < 127) v = *reinterpret_cast<const float4*>(srcp + q * 4);
        *reinterpret_cast<float4*>(&Us[k][dq * 16 + q * 4]) = v;
      }
    }
    __syncthreads();
#pragma unroll 4
    for (int k = 0; k < 32; ++k) {
      float4 tv = *reinterpret_cast<const float4*>(&Wk[k][tg * 4]);
      float4 dv = *reinterpret_cast<const float4*>(&Us[k][dg * 4]);
      fma16(tv, dv, acc);
    }
  }
#pragma unroll
  for (int ti = 0; ti < 4; ++ti) {
    int t = t0 + tg * 4 + ti;
    if (t < 127) {
      float bb = bdt[t];
      float4 o4;
      o4.x = q88(sigmoid_(q88(acc[ti][0] + bb)));
      o4.y = q88(sigmoid_(q88(acc[ti][1] + bb)));
      o4.z = q88(sigmoid_(q88(acc[ti][2] + bb)));
      o4.w = q88(sigmoid_(q88(acc[ti][3] + bb)));
      *reinterpret_cast<float4*>(lam + ((size_t)b * 127 + t) * 128 + dg * 4) = o4;
    }
  }
}

// ---------------- K6: sequential scan + p = y*g; 1 block per batch, thread per d -------------
// 8-slot statically-indexed prefetch ring (rule-20 safe) hides L2 latency.
__global__ __launch_bounds__(128) void k_scan(const float* __restrict__ u, const float* __restrict__ gbuf,
                                              float* __restrict__ lamp) {
  int b = blockIdx.x, d = threadIdx.x;
  const size_t base = (size_t)b * (127 * 128) + d;
  float lm[8], uu[8], gg[8];
#pragma unroll
  for (int j = 0; j < 8; ++j) {
    size_t idx = base + (size_t)j * 128;
    lm[j] = lamp[idx]; uu[j] = u[idx]; gg[j] = gbuf[idx];
  }
  float s = 0.f;
  int t = 0;
  for (int it = 0; it < 15; ++it) {   // t = 0..119
#pragma unroll
    for (int j = 0; j < 8; ++j) {
      float l0 = lm[j], u0 = uu[j], g0 = gg[j];
      s = l0 * s + (1.0f - l0) * u0;
      lamp[base + (size_t)(t + j) * 128] = s * g0;
      int tn = t + j + 8;
      if (tn < 127) {
        size_t idx = base + (size_t)tn * 128;
        lm[j] = lamp[idx]; uu[j] = u[idx]; gg[j] = gbuf[idx];
      }
    }
    t += 8;
  }
  // tail t = 120..126 (slots 0..6)
#pragma unroll
  for (int j = 0; j < 7; ++j) {
    float l0 = lm[j], u0 = uu[j], g0 = gg[j];
    s = l0 * s + (1.0f - l0) * u0;
    lamp[base + (size_t)(120 + j) * 128] = s * g0;
  }
}

// ---------------- K7: fused (h += p@Wout) -> LN -> u/g GEMMs -> silu -------------------------
__global__ __launch_bounds__(256) void k_out_ln_ug(
    const float* __restrict__ p, const float* __restrict__ Wout, float* __restrict__ h,
    const float* __restrict__ lng, const float* __restrict__ lnb,
    const float* __restrict__ Win, const float* __restrict__ Wgate,
    float* __restrict__ u, float* __restrict__ gbuf) {
  __shared__ __align__(16) float As[128][36];
  __shared__ float2 lnpart[8][32];
  __shared__ float mean_s[32], inv_s[32];
  int tid = threadIdx.x;
  int mr = tid & 31, c0 = (tid >> 5) * 16;
  int m0 = blockIdx.x * 32;
  // stage p rows (transposed into As[c][mr])
  {
    const float* src = p + (size_t)(m0 + mr) * 128 + c0;
#pragma unroll
    for (int q = 0; q < 4; ++q) {
      float4 v = *reinterpret_cast<const float4*>(src + q * 4);
      As[c0 + q * 4 + 0][mr] = v.x;
      As[c0 + q * 4 + 1][mr] = v.y;
      As[c0 + q * 4 + 2][mr] = v.z;
      As[c0 + q * 4 + 3][mr] = v.w;
    }
  }
  __syncthreads();
  int tn = tid & 31, tm8 = tid >> 5;
  float acc[4][4] = {};
  {
    const float* wp = Wout + tn * 4;
#pragma unroll 4
    for (int c = 0; c < 128; ++c) {
      float4 bv = *reinterpret_cast<const float4*>(wp + c * 128);
      float4 av = *reinterpret_cast<const float4*>(&As[c][tm8 * 4]);
      fma16(av, bv, acc);
    }
  }
  // hv = h + acc; write back h
  float4 hv[4];
  {
    float* hdst = h + (size_t)m0 * 128 + tn * 4;
#pragma unroll
    for (int i = 0; i < 4; ++i) {
      hv[i] = *reinterpret_cast<float4*>(hdst + (size_t)(tm8 * 4 + i) * 128);
      hv[i].x += acc[i][0]; hv[i].y += acc[i][1]; hv[i].z += acc[i][2]; hv[i].w += acc[i][3];
      *reinterpret_cast<float4*>(hdst + (size_t)(tm8 * 4 + i) * 128) = hv[i];
    }
  }
  __syncthreads();                 // all GEMM reads of As done
  // restage hv transposed: As[c][row]
#pragma unroll
  for (int i = 0; i < 4; ++i) {
    int row = tm8 * 4 + i;
    As[tn * 4 + 0][row] = hv[i].x;
    As[tn * 4 + 1][row] = hv[i].y;
    As[tn * 4 + 2][row] = hv[i].z;
    As[tn * 4 + 3][row] = hv[i].w;
  }
  __syncthreads();
  // LN stats (identical order to k_ln_ug2)
  {
    float s1 = 0.f, s2 = 0.f;
#pragma unroll
    for (int q = 0; q < 4; ++q) {
      float vx = As[c0 + q * 4 + 0][mr];
      float vy = As[c0 + q * 4 + 1][mr];
      float vz = As[c0 + q * 4 + 2][mr];
      float vw = As[c0 + q * 4 + 3][mr];
      s1 += vx + vy + vz + vw;
      s2 = fmaf(vx, vx, s2); s2 = fmaf(vy, vy, s2);
      s2 = fmaf(vz, vz, s2); s2 = fmaf(vw, vw, s2);
    }
    lnpart[tid >> 5][mr] = make_float2(s1, s2);
  }
  __syncthreads();
  if (tid < 32) {
    float s = 0.f, ss = 0.f;
#pragma unroll
    for (int j = 0; j < 8; ++j) { float2 pp = lnpart[j][tid]; s += pp.x; ss += pp.y; }
    float mn = s * (1.0f / 128.0f);
    float var = ss * (1.0f / 128.0f) - mn * mn;
    mean_s[tid] = mn;
    inv_s[tid] = rsqrtf(var + 1e-5f);
  }
  __syncthreads();
  {
    float mnv = mean_s[mr], invv = inv_s[mr];
#pragma unroll
    for (int q = 0; q < 16; ++q) {
      int c = c0 + q;
      As[c][mr] = (As[c][mr] - mnv) * invv * lng[c] + lnb[c];
    }
  }
  __syncthreads();
  // u/g GEMM + silu (identical to k_ln_ug2 tail)
  float accU[4][4] = {}, accG[4][4] = {};
  const float* wpU = Win + tn * 4;
  const float* wpG = Wgate + tn * 4;
#pragma unroll 2
  for (int c = 0; c < 128; ++c) {
    float4 av = *reinterpret_cast<const float4*>(&As[c][tm8 * 4]);
    float4 bu = *reinterpret_cast<const float4*>(wpU + c * 128);
    fma16(av, bu, accU);
    float4 bg = *reinterpret_cast<const float4*>(wpG + c * 128);
    fma16(av, bg, accG);
  }
  float* dstU = u + (size_t)m0 * 128 + tn * 4;
  float* dstG = gbuf + (size_t)m0 * 128 + tn * 4;
#pragma unroll
  for (int i = 0; i < 4; ++i) {
    float4 o4;
    { float xq = q88(accU[i][0]); o4.x = q88(xq * sigmoid_(xq)); }
    { float xq = q88(accU[i][1]); o4.y = q88(xq * sigmoid_(xq)); }
    { float xq = q88(accU[i][2]); o4.z = q88(xq * sigmoid_(xq)); }
    { float xq = q88(accU[i][3]); o4.w = q88(xq * sigmoid_(xq)); }
    *reinterpret_cast<float4*>(dstU + (size_t)(tm8 * 4 + i) * 128) = o4;
    float4 g4;
    { float xq = q88(accG[i][0]); g4.x = q88(xq * sigmoid_(xq)); }
    { float xq = q88(accG[i][1]); g4.y = q88(xq * sigmoid_(xq)); }
    { float xq = q88(accG[i][2]); g4.z = q88(xq * sigmoid_(xq)); }
    { float xq = q88(accG[i][3]); g4.w = q88(xq * sigmoid_(xq)); }
    *reinterpret_cast<float4*>(dstG + (size_t)(tm8 * 4 + i) * 128) = g4;
  }
}

// ---------------- K8: fused (h += p@Wout) -> final LN -> q88 -> transpose to [b][r] ----------
__global__ __launch_bounds__(256) void k_out_lnf(
    const float* __restrict__ p, const float* __restrict__ Wout, const float* __restrict__ h,
    const float* __restrict__ gg, const float* __restrict__ bb, float* __restrict__ xp2q) {
  __shared__ __align__(16) float As[128][36];
  __shared__ float2 lnpart[8][32];
  __shared__ float mean_s[32], inv_s[32];
  int tid = threadIdx.x;
  int mr = tid & 31, c0 = (tid >> 5) * 16;
  int m0 = blockIdx.x * 32;
  {
    const float* src = p + (size_t)(m0 + mr) * 128 + c0;
#pragma unroll
    for (int q = 0; q < 4; ++q) {
      float4 v = *reinterpret_cast<const float4*>(src + q * 4);
      As[c0 + q * 4 + 0][mr] = v.x;
      As[c0 + q * 4 + 1][mr] = v.y;
      As[c0 + q * 4 + 2][mr] = v.z;
      As[c0 + q * 4 + 3][mr] = v.w;
    }
  }
  __syncthreads();
  int tn = tid & 31, tm8 = tid >> 5;
  float acc[4][4] = {};
  {
    const float* wp = Wout + tn * 4;
#pragma unroll 4
    for (int c = 0; c < 128; ++c) {
      float4 bv = *reinterpret_cast<const float4*>(wp + c * 128);
      float4 av = *reinterpret_cast<const float4*>(&As[c][tm8 * 4]);
      fma16(av, bv, acc);
    }
  }
  float4 hv[4];
  {
    const float* hsrc = h + (size_t)m0 * 128 + tn * 4;
#pragma unroll
    for (int i = 0; i < 4; ++i) {
      hv[i] = *reinterpret_cast<const float4*>(hsrc + (size_t)(tm8 * 4 + i) * 128);
      hv[i].x += acc[i][0]; hv[i].y += acc[i][1]; hv[i].z += acc[i][2]; hv[i].w += acc[i][3];
    }
  }
  __syncthreads();
#pragma unroll
  for (int i = 0; i < 4; ++i) {
    int row = tm8 * 4 + i;
    As[tn * 4 + 0][row] = hv[i].x;
    As[tn * 4 + 1][row] = hv[i].y;
    As[tn * 4 + 2][row] = hv[i].z;
    As[tn * 4 + 3][row] = hv[i].w;
  }
  __syncthreads();
  {
    float s1 = 0.f, s2 = 0.f;
#pragma unroll
    for (int q = 0; q < 4; ++q) {
      float vx = As[c0 + q * 4 + 0][mr];
      float vy = As[c0 + q * 4 + 1][mr];
      float vz = As[c0 + q * 4 + 2][mr];
      float vw = As[c0 + q * 4 + 3][mr];
      s1 += vx + vy + vz + vw;
      s2 = fmaf(vx, vx, s2); s2 = fmaf(vy, vy, s2);
      s2 = fmaf(vz, vz, s2); s2 = fmaf(vw, vw, s2);
    }
    lnpart[tid >> 5][mr] = make_float2(s1, s2);
  }
  __syncthreads();
  if (tid < 32) {
    float s = 0.f, ss = 0.f;
#pragma unroll
    for (int j = 0; j < 8; ++j) { float2 pp = lnpart[j][tid]; s += pp.x; ss += pp.y; }
    float mn = s * (1.0f / 128.0f);
    float var = ss * (1.0f / 128.0f) - mn * mn;
    mean_s[tid] = mn;
    inv_s[tid] = rsqrtf(var + 1e-5f);
  }
  __syncthreads();
  {
    float mnv = mean_s[mr], invv = inv_s[mr];
    int row = m0 + mr;
    int b = row / 127, k = row % 127;
#pragma unroll
    for (int q = 0; q < 16; ++q) {
      int c = c0 + q;
      float hn = (As[c][mr] - mnv) * invv * gg[c] + bb[c];
      xp2q[((size_t)b * 128 + c) * 127 + k] = q88(hn);
    }
  }
}

// ---------------- K9: flat contraction, 8b x 4o tile, reg-pipelined, r-split x128 ------------
// C[b,o] = sum_r Aq[b,r]*q88(Wf[o,r]).  grid (24 o-tiles x 128 rs), 128 threads.
// 4 chunks of 32 r per block; next chunk's loads issued before computing current.
__global__ __launch_bounds__(128) void k_flat(const float* __restrict__ Aq, const float* __restrict__ Wf,
                                              float* __restrict__ partF) {
  __shared__ float As[32][36];    // [r][b] * 2^-8
  __shared__ float Ws[32][132];   // [r][o] rintf(256*w)
  int ot = blockIdx.x, rs = blockIdx.y;
  int tid = threadIdx.x;
  int og = tid & 31, bsub = tid >> 5;
  int o0 = ot * 128;
  int r0 = rs * 128;               // virtual R = 16384, zero-padded past 16256
  float acc[8][4] = {};

  const int wq4 = tid & 3;         // quad-pair within W row
  const int wrow_l = tid >> 2;     // 0..31, +32 per pass
  const int aq = tid >> 5;         // A quad group
  const int ab = tid & 31;         // A b-row

  float4 wreg[4][2];
  float4 areg[2];

  auto loadch = [&](int rb) {
#pragma unroll
    for (int p = 0; p < 4; ++p) {
      const float* wrow = Wf + (size_t)(o0 + wrow_l + 32 * p) * Rred;
#pragma unroll
      for (int q = 0; q < 2; ++q) {
        int rr = rb + wq4 * 8 + q * 4;
        wreg[p][q] = (rr < Rred) ? *reinterpret_cast<const float4*>(wrow + rr)
                                 : make_float4(0.f, 0.f, 0.f, 0.f);
      }
    }
#pragma unroll
    for (int i = 0; i < 2; ++i) {
      int rr = rb + aq * 4 + 16 * i;
      areg[i] = (rr < Rred) ? *reinterpret_cast<const float4*>(Aq + (size_t)ab * Rred + rr)
                            : make_float4(0.f, 0.f, 0.f, 0.f);
    }
  };

  loadch(r0);
  for (int ch = 0; ch < 4; ++ch) {
    __syncthreads();
#pragma unroll
    for (int p = 0; p < 4; ++p) {
      int oc = wrow_l + 32 * p;
#pragma unroll
      for (int q = 0; q < 2; ++q) {
        int rl = wq4 * 8 + q * 4;
        Ws[rl + 0][oc] = rintf(wreg[p][q].x * 256.0f);
        Ws[rl + 1][oc] = rintf(wreg[p][q].y * 256.0f);
        Ws[rl + 2][oc] = rintf(wreg[p][q].z * 256.0f);
        Ws[rl + 3][oc] = rintf(wreg[p][q].w * 256.0f);
      }
    }
#pragma unroll
    for (int i = 0; i < 2; ++i) {
      int rl = aq * 4 + 16 * i;
      As[rl + 0][ab] = areg[i].x * 0.00390625f;
      As[rl + 1][ab] = areg[i].y * 0.00390625f;
      As[rl + 2][ab] = areg[i].z * 0.00390625f;
      As[rl + 3][ab] = areg[i].w * 0.00390625f;
    }
    __syncthreads();
    if (ch < 3) loadch(r0 + (ch + 1) * 32);
#pragma unroll 4
    for (int rl = 0; rl < 32; ++rl) {
      float4 w  = *reinterpret_cast<const float4*>(&Ws[rl][og * 4]);
      float4 a0 = *reinterpret_cast<const float4*>(&As[rl][bsub * 8]);
      float4 a1 = *reinterpret_cast<const float4*>(&As[rl][bsub * 8 + 4]);
      float a[8] = {a0.x, a0.y, a0.z, a0.w, a1.x, a1.y, a1.z, a1.w};
#pragma unroll
      for (int bi = 0; bi < 8; ++bi) {
        acc[bi][0] = fmaf(a[bi], w.x, acc[bi][0]);
        acc[bi][1] = fmaf(a[bi], w.y, acc[bi][1]);
        acc[bi][2] = fmaf(a[bi], w.z, acc[bi][2]);
        acc[bi][3] = fmaf(a[bi], w.w, acc[bi][3]);
      }
    }
  }
#pragma unroll
  for (int bi = 0; bi < 8; ++bi) {
    int b = bsub * 8 + bi;
    float* dst = partF + ((size_t)rs * 32 + b) * 3072 + o0 + og * 4;
    *reinterpret_cast<float4*>(dst) = make_float4(acc[bi][0], acc[bi][1], acc[bi][2], acc[bi][3]);
  }
}

// ---------------- K10: reduce 128 r-partials + bias -> y_feat (q88) --------------------------
__global__ __launch_bounds__(256) void k_yfeat(const float* __restrict__ partF, const float* __restrict__ bqf,
                                               float* __restrict__ yf) {
  int b = blockIdx.x, oc = blockIdx.y;
  int o = oc * 256 + threadIdx.x;
  float s = bqf[o];
  for (int r = 0; r < 128; ++r) s += partF[((size_t)r * 32 + b) * 3072 + o];
  yf[(size_t)b * 3072 + o] = q88(s);
}

// ---------------- K11: head conv1x1 over y_feat ----------------------------------------------
__global__ __launch_bounds__(256) void k_head2(const float* __restrict__ yf, const float* __restrict__ wqh,
                                               const float* __restrict__ bqh, float* __restrict__ out) {
  int b = blockIdx.x;
  int tid = threadIdx.x;
  __shared__ float ys[3072];
#pragma unroll
  for (int i = 0; i < 12; ++i) ys[tid + 256 * i] = yf[(size_t)b * 3072 + tid + 256 * i];
  __syncthreads();
  if (tid < 48) {
    int oh = tid / 24, f = tid % 24;
    float acc = bqh[oh];
    for (int d = 0; d < 128; ++d) acc = fmaf(ys[d * 24 + f], wqh[oh * 128 + d], acc);
    out[(size_t)b * 48 + oh * 24 + f] = q88(acc);
  }
}

}  // namespace

extern "C" void kernel_launch(void* const* d_in, const int* in_sizes, int n_in,
                              void* d_out, int out_size, void* d_ws, size_t ws_size,
                              hipStream_t stream) {
  const float* x      = (const float*)d_in[0];
  const float* wproj  = (const float*)d_in[1];
  const float* bproj  = (const float*)d_in[2];
  const float* wpatch = (const float*)d_in[3];
  const float* bpatch = (const float*)d_in[4];
  const float* pe     = (const float*)d_in[5];
  const float* pescal = (const float*)d_in[6];
  const float* lng    = (const float*)d_in[7];
  const float* lnb    = (const float*)d_in[8];
  const float* win    = (const float*)d_in[9];
  const float* wgate  = (const float*)d_in[10];
  const float* wout   = (const float*)d_in[11];
  const float* wdt    = (const float*)d_in[12];
  const float* bdt    = (const float*)d_in[13];
  const float* lnfg   = (const float*)d_in[14];
  const float* lnfb   = (const float*)d_in[15];
  const float* wflat  = (const float*)d_in[16];
  const float* bflat  = (const float*)d_in[17];
  const float* whead  = (const float*)d_in[18];
  const float* bhead  = (const float*)d_in[19];
  float* out = (float*)d_out;
  float* ws  = (float*)d_ws;

  // ws layout (float offsets)
  constexpr size_t O_WQPROJ  = 0;         // 1024
  constexpr size_t O_BQPROJ  = 1024;      // 128
  constexpr size_t O_WPQ     = 2048;      // 262144   [j][c][d]
  constexpr size_t O_BQPATCH = 264192;    // 128
  constexpr size_t O_WQHEAD  = 264320;    // 256
  constexpr size_t O_BQHEAD  = 264576;    // 2 (pad 128)
  constexpr size_t O_BQFLAT  = 264704;    // 3072
  constexpr size_t O_XPQ     = 267776;    // 4194304  [b][l][c]
  constexpr size_t O_PARTJ   = 4462080;   // 4*520192
  constexpr size_t O_H       = 6542848;   // 520192   [b][k][d]
  constexpr size_t O_U       = 7063040;   // 520192
  constexpr size_t O_G       = 7583232;   // 520192
  constexpr size_t O_P       = 8103424;   // 520192   lam, then p = y*g
  constexpr size_t O_XP2Q    = 8623616;   // 520192   [b][r] (= [b][d][k])
  constexpr size_t O_PARTF   = 9143808;   // 128*98304 = 12582912
  constexpr size_t O_YF      = 21726720;  // 98304

  k_quant<<<(262144 + 4610 + 255) / 256, 256, 0, stream>>>(
      wproj, bproj, wpatch, bpatch, whead, bhead, bflat,
      ws + O_WQPROJ, ws + O_BQPROJ, ws + O_WPQ, ws + O_BQPATCH,
      ws + O_WQHEAD, ws + O_BQHEAD, ws + O_BQFLAT);

  k_proj<<<2048, 256, 0, stream>>>(x, ws + O_WQPROJ, ws + O_BQPROJ, ws + O_XPQ);

  {
    dim3 g(127, 4);
    k_patch<<<g, 256, 0, stream>>>(ws + O_XPQ, ws + O_WPQ, ws + O_PARTJ);
  }
  k_combine<<<2032, 256, 0, stream>>>(ws + O_PARTJ, ws + O_BQPATCH, pe, pescal, ws + O_H);

  k_ln_ug2<<<127, 256, 0, stream>>>(ws + O_H, lng, lnb, win, wgate, ws + O_U, ws + O_G);

  for (int i = 0; i < 4; ++i) {
    {
      dim3 gl(32, 4);
      k_lamg<<<gl, 256, 0, stream>>>(ws + O_U, wdt + (size_t)i * 16129, bdt + (size_t)i * 127,
                                     ws + O_P);
    }
    k_scan<<<32, 128, 0, stream>>>(ws + O_U, ws + O_G, ws + O_P);
    if (i < 3) {
      k_out_ln_ug<<<127, 256, 0, stream>>>(ws + O_P, wout + (size_t)i * 16384, ws + O_H,
                                           lng + (i + 1) * 128, lnb + (i + 1) * 128,
                                           win + (size_t)(i + 1) * 16384,
                                           wgate + (size_t)(i + 1) * 16384,
                                           ws + O_U, ws + O_G);
    } else {
      k_out_lnf<<<127, 256, 0, stream>>>(ws + O_P, wout + (size_t)i * 16384, ws + O_H,
                                         lnfg, lnfb, ws + O_XP2Q);
    }
  }

  {
    dim3 g(24, 128);
    k_flat<<<g, 128, 0, stream>>>(ws + O_XP2Q, wflat, ws + O_PARTF);
  }
  {
    dim3 gy(32, 12);
    k_yfeat<<<gy, 256, 0, stream>>>(ws + O_PARTF, ws + O_BQFLAT, ws + O_YF);
  }
  k_head2<<<32, 256, 0, stream>>>(ws + O_YF, ws + O_WQHEAD, ws + O_BQHEAD, out);
}